// Round 11
// baseline (806.491 us; speedup 1.0000x reference)
//
#include <hip/hip_runtime.h>

typedef __attribute__((ext_vector_type(8))) short bf16x8;
typedef __attribute__((ext_vector_type(4))) float f32x4;

#define NBATCH 4
#define LSEQ   4096
#define DMODEL 1024
#define DI     2048
#define DST    16
#define NCHUNK 128
#define CLEN   (LSEQ/NCHUNK)   // 32
#define KSPLIT 8               // split-K factor for Bs GEMM

// ---------------- helpers ----------------
__device__ __forceinline__ ushort f2bf(float x){
  union { float f; unsigned u; } v; v.f = x;
  unsigned r = v.u + 0x7FFFu + ((v.u >> 16) & 1u);
  return (ushort)(r >> 16);
}
__device__ __forceinline__ float bf2f(ushort h){
  union { unsigned u; float f; } v; v.u = ((unsigned)h) << 16;
  return v.f;
}
__device__ __forceinline__ float fexp2(float x){
  float r; asm("v_exp_f32 %0, %1" : "=v"(r) : "v"(x)); return r;
}
__device__ __forceinline__ float fsilu(float x){
  return x * __builtin_amdgcn_rcpf(1.f + __expf(-x));
}
__device__ __forceinline__ void gld_lds16(const ushort* g, ushort* l){
  __builtin_amdgcn_global_load_lds(
    (const __attribute__((address_space(1))) unsigned int*)g,
    (__attribute__((address_space(3))) unsigned int*)l, 16, 0, 0);
}

// ---------------- elementwise cast f32 -> bf16 (x4 vectorized) ----------------
__global__ void cast_f32_bf16(const float* __restrict__ in, ushort* __restrict__ out, int n4){
  int i = blockIdx.x*blockDim.x + threadIdx.x;
  if (i >= n4) return;
  float4 v = ((const float4*)in)[i];
  ushort4 o; o.x=f2bf(v.x); o.y=f2bf(v.y); o.z=f2bf(v.z); o.w=f2bf(v.w);
  ((ushort4*)out)[i] = o;
}

// ---------------- transpose + cast: out[c][r] = bf16(in[r][c]) ----------------
__global__ void transpose_cast(const float* __restrict__ in, ushort* __restrict__ out, int R, int C){
  __shared__ float tile[32][33];
  int c0 = blockIdx.x*32, r0 = blockIdx.y*32;
  int tx = threadIdx.x, ty = threadIdx.y;   // 32 x 8
  #pragma unroll
  for (int i=0;i<4;i++){
    int r = r0 + ty + i*8;
    if (r < R && (c0+tx) < C) tile[ty+i*8][tx] = in[(size_t)r*C + c0 + tx];
  }
  __syncthreads();
  #pragma unroll
  for (int i=0;i<4;i++){
    int c = c0 + ty + i*8;
    if (c < C && (r0+tx) < R) out[(size_t)c*R + r0 + tx] = f2bf(tile[tx][ty+i*8]);
  }
}

// A2n = -exp(A_log) * log2(e)
__global__ void prep_a2(const float* __restrict__ A_log, float* __restrict__ A2n, int n){
  int i = blockIdx.x*blockDim.x + threadIdx.x;
  if (i < n) A2n[i] = -expf(A_log[i]) * 1.4426950408889634f;
}

// Check whether a2[c][s] == (s+1)*a2[c][0] for all channels (enables 1-exp scan path).
__global__ void check_a2(const float* __restrict__ A2n, int* __restrict__ flag){
  int c = blockIdx.x*blockDim.x + threadIdx.x;
  if (c >= DI) return;
  const float* a = A2n + (size_t)c*DST;
  float a0 = a[0];
  int bad = 0;
  #pragma unroll
  for (int s=1;s<DST;s++){
    float want = (float)(s+1)*a0;
    if (fabsf(a[s] - want) > 1e-4f*fabsf(want) + 1e-12f) bad = 1;
  }
  if (bad) atomicOr(flag, 1);
}

// ======== pipelined bf16 MFMA GEMM with REGISTER FRAGMENT DOUBLE-BUFFER ========
// 512 threads = 8 waves, BK=32, 4 LDS buffers, stage(t+3) lookahead, counted
// vmcnt (leave L in steady state so tile t+2 is visible at each barrier).
// Step t: MFMA uses fragments read during step t-1 (registers), while this
// step's ds_reads fetch step t+1's fragments -> LDS reads overlap matrix pipe.
// Race-safe: stage(t+3) targets buf (t-1)%4 whose reads finished before the
// t-1 barrier; reads during t target buf (t+1)%4.
template<int BM, int BN, int WM, int WN, int MODE>
__global__ __launch_bounds__(512, 2)
void gemm8(const ushort* __restrict__ A, const ushort* __restrict__ Bm, const int K,
           void* __restrict__ out0, void* __restrict__ out1, const float* __restrict__ bias)
{
  constexpr int TM = BM/WM, TN = BN/WN;
  constexpr int MR = TM/16, NR = TN/16;
  constexpr int AI = BM/128, BI = BN/128;
  constexpr int L  = AI + BI;
  constexpr int LA = 3;                          // lookahead tiles (DEPTH=4)
  constexpr int SA   = BM*32;
  constexpr int SBUF = (BM+BN)*32;
  __shared__ __align__(16) ushort lds[4*SBUF];

  const int tid = threadIdx.x;
  const int w = tid >> 6, lane = tid & 63;
  const int lm = lane & 15, lq = lane >> 4;
  const int wm = w / WN, wn = w % WN;
  const int bn = blockIdx.x, bm = blockIdx.y;
  const int nt = K >> 5;                         // even for all our K

  const size_t Abase = (size_t)bm*BM*K;
  const size_t Bbase = (size_t)bn*BN*K;

  f32x4 acc[MR][NR];
  #pragma unroll
  for (int i=0;i<MR;i++)
    #pragma unroll
    for (int j=0;j<NR;j++) acc[i][j] = (f32x4){0.f,0.f,0.f,0.f};

  auto stage = [&](int t, int bufidx){
    ushort* buf = &lds[(size_t)bufidx*SBUF];
    const int k0 = t*32;
    #pragma unroll
    for (int i=0;i<AI;i++){
      int slot = (w*AI+i)*64 + lane;
      int row  = slot >> 2;
      int s16  = (lane&3) ^ ((row>>1)&3);
      gld_lds16(A + Abase + (size_t)row*K + k0 + s16*8, buf + (w*AI+i)*512);
    }
    #pragma unroll
    for (int i=0;i<BI;i++){
      int slot = (w*BI+i)*64 + lane;
      int row  = slot >> 2;
      int s16  = (lane&3) ^ ((row>>1)&3);
      gld_lds16(Bm + Bbase + (size_t)row*K + k0 + s16*8, buf + SA + (w*BI+i)*512);
    }
  };

  bf16x8 afA[MR], bfA[NR], afB[MR], bfB[NR];

#define READ_FRAGS(AF, BF, BIDX)                                              \
  {                                                                           \
    const ushort* bufn = &lds[(size_t)(BIDX)*SBUF];                           \
    _Pragma("unroll")                                                         \
    for (int ni=0;ni<NR;ni++){                                                \
      int row = wn*TN + ni*16 + lm;                                           \
      BF[ni] = *(const bf16x8*)&bufn[SA + row*32 + ((lq ^ ((row>>1)&3))<<3)]; \
    }                                                                         \
    _Pragma("unroll")                                                         \
    for (int mi=0;mi<MR;mi++){                                                \
      int row = wm*TM + mi*16 + lm;                                           \
      AF[mi] = *(const bf16x8*)&bufn[row*32 + ((lq ^ ((row>>1)&3))<<3)];      \
    }                                                                         \
  }

#define GSTEP(T, AFC, BFC, AFN, BFN)                                          \
  {                                                                           \
    if ((T)+LA < nt) stage((T)+LA, ((T)+LA) & 3);                             \
    if ((T)+1 < nt) READ_FRAGS(AFN, BFN, ((T)+1) & 3);                        \
    __builtin_amdgcn_s_setprio(1);                                            \
    _Pragma("unroll")                                                         \
    for (int mi=0;mi<MR;mi++)                                                 \
      _Pragma("unroll")                                                       \
      for (int ni=0;ni<NR;ni++)                                               \
        acc[mi][ni] = __builtin_amdgcn_mfma_f32_16x16x32_bf16(AFC[mi], BFC[ni], acc[mi][ni], 0, 0, 0); \
    __builtin_amdgcn_s_setprio(0);                                            \
    if ((T)+1 < nt){                                                          \
      if ((T)+LA < nt) __builtin_amdgcn_s_waitcnt(0xF70 | L);                 \
      else             __builtin_amdgcn_s_waitcnt(0xF70);                     \
      __builtin_amdgcn_sched_barrier(0);                                      \
      __builtin_amdgcn_s_barrier();                                           \
    }                                                                         \
  }

  // prologue: 3 tiles in flight; wait so tiles 0,1 are visible; read frags(0)
  stage(0, 0); stage(1, 1); stage(2, 2);
  __builtin_amdgcn_s_waitcnt(0xF70 | L);
  __builtin_amdgcn_sched_barrier(0);
  __builtin_amdgcn_s_barrier();
  READ_FRAGS(afA, bfA, 0);

  for (int t = 0; t < nt; t += 2){
    GSTEP(t,   afA, bfA, afB, bfB);
    GSTEP(t+1, afB, bfB, afA, bfA);
  }
#undef GSTEP
#undef READ_FRAGS

  const int row0 = bm*BM + wm*TM;
  const int col0 = bn*BN + wn*TN;
  #pragma unroll
  for (int mi=0;mi<MR;mi++){
    #pragma unroll
    for (int ni=0;ni<NR;ni++){
      int c = col0 + ni*16 + lm;
      int rbase = row0 + mi*16 + lq*4;
      #pragma unroll
      for (int j=0;j<4;j++){
        float v = acc[mi][ni][j];
        size_t rr = (size_t)(rbase + j);
        if (MODE==0){
          if (c < 2048) ((ushort*)out0)[rr*2048 + c] = f2bf(v);
          else          ((ushort*)out1)[rr*2048 + (c-2048)] = f2bf(fsilu(v));
        } else if (MODE==1){
          float u = v + bias[c];
          float sp = (u > 15.f) ? u : logf(1.f + __expf(u));
          ((ushort*)out0)[rr*2048 + c] = f2bf(sp);
        } else if (MODE==2){
          ((float*)out0)[rr*1024 + c] = v;
        }
      }
    }
  }
}

// ---------------- split-K skinny GEMM for Bs: 4096x16x2048, partials over K ----------------
__global__ __launch_bounds__(256, 2)
void gemm_bs(const ushort* __restrict__ A, const ushort* __restrict__ WxT,
             float* __restrict__ partial)
{
  __shared__ __align__(16) ushort As[128*32];
  __shared__ __align__(16) ushort Bs[16*32];
  const int tid = threadIdx.x;
  const int wave = tid >> 6, lane = tid & 63;
  const int kc = blockIdx.x, bm = blockIdx.y;
  const int lm = lane & 15, kk = (lane >> 4) * 8;
  const int KC = DI / KSPLIT;    // 256
  f32x4 acc[2];
  acc[0] = (f32x4){0.f,0.f,0.f,0.f};
  acc[1] = (f32x4){0.f,0.f,0.f,0.f};
  const size_t Abase = (size_t)bm*128*DI;
  for (int k0 = kc*KC; k0 < (kc+1)*KC; k0 += 32) {
    __syncthreads();
    #pragma unroll
    for (int j=0;j<2;j++){
      int f = j*2048 + tid*8;
      gld_lds16(A + Abase + (size_t)(f>>5)*DI + k0 + (f&31), &As[j*2048 + wave*512]);
    }
    if (wave == 0){
      int f = lane*8;            // 16 rows x 32 cols
      gld_lds16(WxT + (size_t)(f>>5)*DI + k0 + (f&31), &Bs[0]);
    }
    __syncthreads();
    bf16x8 bfv = *(const bf16x8*)&Bs[lm*32 + kk];
    #pragma unroll
    for (int mi=0;mi<2;mi++){
      bf16x8 af = *(const bf16x8*)&As[(wave*32+mi*16+lm)*32 + kk];
      acc[mi] = __builtin_amdgcn_mfma_f32_16x16x32_bf16(af, bfv, acc[mi], 0, 0, 0);
    }
  }
  float* outp = partial + (size_t)kc*LSEQ*DST;
  #pragma unroll
  for (int mi=0;mi<2;mi++){
    int rbase = bm*128 + wave*32 + mi*16 + (lane>>4)*4;
    #pragma unroll
    for (int j=0;j<4;j++)
      outp[(size_t)(rbase+j)*DST + lm] = acc[mi][j];
  }
}

// sum the KSPLIT partials -> BsB
__global__ void reduce_bs(const float* __restrict__ partial, float* __restrict__ out, int n4){
  int i = blockIdx.x*blockDim.x + threadIdx.x;
  if (i >= n4) return;
  float4 s = ((const float4*)partial)[i];
  #pragma unroll
  for (int k=1;k<KSPLIT;k++){
    float4 v = ((const float4*)(partial + (size_t)k*LSEQ*DST))[i];
    s.x += v.x; s.y += v.y; s.z += v.z; s.w += v.w;
  }
  ((float4*)out)[i] = s;
}

// ---------------- depthwise causal conv K=4 + silu, bf16 in/out (one batch) ----------------
__global__ __launch_bounds__(256)
void conv_silu(const ushort* __restrict__ xs_raw, const float* __restrict__ w,
               const float* __restrict__ cb, ushort* __restrict__ out)
{
  int idx = blockIdx.x*256 + threadIdx.x;   // (LSEQ/8)*DI threads
  int c  = idx & (DI-1);
  int l8 = idx >> 11;                       // 0..511
  int l0 = l8*8;
  float w0=w[c*4+0], w1=w[c*4+1], w2=w[c*4+2], w3=w[c*4+3];
  float bias = cb[c];
  const ushort* base = xs_raw + c;
  float v[11];
  #pragma unroll
  for (int i=0;i<11;i++){
    int t = l0 - 3 + i;
    v[i] = (t >= 0) ? bf2f(base[(size_t)t*DI]) : 0.f;
  }
  ushort* ob = out + (size_t)l0*DI + c;
  #pragma unroll
  for (int i=0;i<8;i++){
    float acc = bias + v[i]*w0 + v[i+1]*w1 + v[i+2]*w2 + v[i+3]*w3;
    ob[(size_t)i*DI] = f2bf(fsilu(acc));
  }
}

// decay helpers: fast path builds g^(s+1) from one exp (valid when a2[s]=(s+1)*a2[0])
__device__ __forceinline__ void build_pw(float g, float* pw){
  pw[0]=g;        pw[1]=g*g;       pw[2]=pw[1]*g;    pw[3]=pw[1]*pw[1];
  pw[4]=pw[3]*g;  pw[5]=pw[3]*pw[1]; pw[6]=pw[3]*pw[2]; pw[7]=pw[3]*pw[3];
  pw[8]=pw[7]*g;  pw[9]=pw[7]*pw[1]; pw[10]=pw[7]*pw[2]; pw[11]=pw[7]*pw[3];
  pw[12]=pw[7]*pw[4]; pw[13]=pw[7]*pw[5]; pw[14]=pw[7]*pw[6]; pw[15]=pw[7]*pw[7];
}

// Carry tensors use SoA layout: hlocal/hstart[((ch*DST + s)*DI) + c]

// ---------------- scan phase 1: per-chunk local scan, h0=0 (one batch) ----------------
__global__ __launch_bounds__(256)
void scan_phase1(const ushort* __restrict__ dtb, const float* __restrict__ bsb,
                 const float* __restrict__ A2n, float* __restrict__ hlocal,
                 float* __restrict__ sumdt, const int* __restrict__ flagp)
{
  __shared__ __align__(16) float bs_s[CLEN][DST];
  const int c  = blockIdx.x*256 + threadIdx.x;
  const int ch = blockIdx.y;
  if (threadIdx.x < CLEN*DST/4)
    ((float4*)bs_s)[threadIdx.x] = ((const float4*)(bsb + (size_t)ch*CLEN*DST))[threadIdx.x];
  __syncthreads();
  float h[DST];
  #pragma unroll
  for (int s=0;s<DST;s++) h[s] = 0.f;
  float sdt = 0.f;
  const ushort* dtp = dtb + (size_t)ch*CLEN*DI + c;
  if (flagp[0] == 0){
    const float a0 = A2n[(size_t)c*DST];
    #pragma unroll 4
    for (int t=0;t<CLEN;t++){
      float d = bf2f(dtp[(size_t)t*DI]);
      sdt += d;
      float pw[DST];
      build_pw(fexp2(a0*d), pw);
      #pragma unroll
      for (int s=0;s<DST;s++) h[s] = fmaf(h[s], pw[s], bs_s[t][s]);
    }
  } else {
    float a2[DST];
    #pragma unroll
    for (int i=0;i<4;i++) *(float4*)&a2[i*4] = *(const float4*)&A2n[(size_t)c*DST + i*4];
    #pragma unroll 2
    for (int t=0;t<CLEN;t++){
      float d = bf2f(dtp[(size_t)t*DI]);
      sdt += d;
      #pragma unroll
      for (int s=0;s<DST;s++) h[s] = fmaf(h[s], fexp2(a2[s]*d), bs_s[t][s]);
    }
  }
  size_t o = (size_t)ch*DST*DI + c;
  #pragma unroll
  for (int s=0;s<DST;s++) hlocal[o + (size_t)s*DI] = h[s];
  sumdt[(size_t)ch*DI + c] = sdt;
}

// ---------------- scan phase 2: chunk-level prefix over NCHUNK chunks ----------------
__global__ void scan_phase2(const float* __restrict__ hlocal, const float* __restrict__ sumdt,
                            const float* __restrict__ A2n, float* __restrict__ hstart)
{
  int id = blockIdx.x*blockDim.x + threadIdx.x;   // DI*DST = 32768
  int c = id & (DI-1);
  int s = id >> 11;
  float a2 = A2n[(size_t)c*DST + s];
  float h = 0.f;
  for (int ch=0; ch<NCHUNK; ++ch){
    size_t o = ((size_t)ch*DST + s)*DI + c;
    hstart[o] = h;
    float sd = sumdt[(size_t)ch*DI + c];
    h = fmaf(h, fexp2(a2*sd), hlocal[o]);
  }
}

// ---------------- scan phase 3: replay with carry, emit y*silu(z) bf16 ----------------
__global__ __launch_bounds__(256)
void scan_phase3(const ushort* __restrict__ dtb, const float* __restrict__ bsb,
                 const float* __restrict__ A2n, const float* __restrict__ hstart,
                 const ushort* __restrict__ xsbf, const ushort* __restrict__ szb,
                 const float* __restrict__ Dv, ushort* __restrict__ ybf,
                 const int* __restrict__ flagp)
{
  __shared__ __align__(16) float bs_s[CLEN][DST];
  const int c  = blockIdx.x*256 + threadIdx.x;
  const int ch = blockIdx.y;
  if (threadIdx.x < CLEN*DST/4)
    ((float4*)bs_s)[threadIdx.x] = ((const float4*)(bsb + (size_t)ch*CLEN*DST))[threadIdx.x];
  __syncthreads();
  float h[DST];
  size_t ho = (size_t)ch*DST*DI + c;
  #pragma unroll
  for (int s=0;s<DST;s++) h[s] = hstart[ho + (size_t)s*DI];
  const float Dc = Dv[c];
  const size_t base = (size_t)ch*CLEN*DI + c;
  const ushort* dtp = dtb + base;
  const ushort* xp  = xsbf + base;
  const ushort* szp = szb + base;
  ushort* yp = ybf + base;
  if (flagp[0] == 0){
    const float a0 = A2n[(size_t)c*DST];
    #pragma unroll 4
    for (int t=0;t<CLEN;t++){
      float d = bf2f(dtp[(size_t)t*DI]);
      float pw[DST];
      build_pw(fexp2(a0*d), pw);
      #pragma unroll
      for (int s=0;s<DST;s++) h[s] = fmaf(h[s], pw[s], bs_s[t][s]);
      float ysum = ((h[0]+h[1])+(h[2]+h[3])) + ((h[4]+h[5])+(h[6]+h[7]))
                 + ((h[8]+h[9])+(h[10]+h[11])) + ((h[12]+h[13])+(h[14]+h[15]));
      float xv = bf2f(xp[(size_t)t*DI]);
      float yv = fmaf(Dc, xv, ysum);
      yp[(size_t)t*DI] = f2bf(yv * bf2f(szp[(size_t)t*DI]));
    }
  } else {
    float a2[DST];
    #pragma unroll
    for (int i=0;i<4;i++) *(float4*)&a2[i*4] = *(const float4*)&A2n[(size_t)c*DST + i*4];
    #pragma unroll 2
    for (int t=0;t<CLEN;t++){
      float d = bf2f(dtp[(size_t)t*DI]);
      #pragma unroll
      for (int s=0;s<DST;s++) h[s] = fmaf(h[s], fexp2(a2[s]*d), bs_s[t][s]);
      float ysum = ((h[0]+h[1])+(h[2]+h[3])) + ((h[4]+h[5])+(h[6]+h[7]))
                 + ((h[8]+h[9])+(h[10]+h[11])) + ((h[12]+h[13])+(h[14]+h[15]));
      float xv = bf2f(xp[(size_t)t*DI]);
      float yv = fmaf(Dc, xv, ysum);
      yp[(size_t)t*DI] = f2bf(yv * bf2f(szp[(size_t)t*DI]));
    }
  }
}

// ---------------- launch ----------------
extern "C" void kernel_launch(void* const* d_in, const int* in_sizes, int n_in,
                              void* d_out, int out_size, void* d_ws, size_t ws_size,
                              hipStream_t stream)
{
  if (n_in < 10) return;
  const float* x     = (const float*)d_in[0];
  const float* W_in  = (const float*)d_in[1];
  const float* convw = (const float*)d_in[2];
  const float* convb = (const float*)d_in[3];
  const float* A_log = (const float*)d_in[4];
  const float* Dvec  = (const float*)d_in[5];
  const float* W_x   = (const float*)d_in[6];
  const float* W_dt  = (const float*)d_in[7];
  const float* b_dt  = (const float*)d_in[8];
  const float* W_out = (const float*)d_in[9];
  float* out = (float*)d_out;

  char* p = (char*)d_ws;
  auto alloc = [&](size_t n){ char* r = p; p += (n + 255) & ~(size_t)255; return r; };
  // weights (once)
  ushort* WinT   = (ushort*)alloc((size_t)(2*DI)*DMODEL*2);   //  8.4 MB
  ushort* WdtT   = (ushort*)alloc((size_t)DI*DI*2);           //  8.4 MB
  ushort* WoutT  = (ushort*)alloc((size_t)DMODEL*DI*2);       //  4.2 MB
  ushort* WxT    = (ushort*)alloc((size_t)DST*DI*2);          //  64 KB
  float*  A2n    = (float*)alloc((size_t)DI*DST*4);           //  0.1 MB
  int*    flag   = (int*)alloc(256);
  // per-batch activations (reused across the 4 batches)
  ushort* xbf    = (ushort*)alloc((size_t)LSEQ*DMODEL*2);     //  8.4 MB
  ushort* xsr    = (ushort*)alloc((size_t)LSEQ*DI*2);         // 16.8 MB raw xs; dead after conv -> reused as hlocal
  ushort* szb    = (ushort*)alloc((size_t)LSEQ*DI*2);         // 16.8 MB silu(z)
  ushort* xsb    = (ushort*)alloc((size_t)LSEQ*DI*2);         // 16.8 MB conv+silu
  ushort* dtb    = (ushort*)alloc((size_t)LSEQ*DI*2);         // 16.8 MB dt
  ushort* ybf    = (ushort*)alloc((size_t)LSEQ*DI*2);         // 16.8 MB y
  float*  BsB    = (float*)alloc((size_t)LSEQ*DST*4);         //  0.3 MB
  float*  hstart = (float*)alloc((size_t)NCHUNK*DI*DST*4);    // 16.8 MB (aliased by BsP pre-scan)
  float*  sumdt  = (float*)alloc((size_t)NCHUNK*DI*4);        //  1.0 MB
  if ((size_t)(p - (char*)d_ws) > ws_size) return;   // ws too small: no OOB
  float* hlocal = (float*)xsr;   // 16.8 MB == xsr size; xsr dead after conv,
                                 // hlocal dead after phase2 (before next batch's gemm0 rewrites xsr)
  float* BsP = hstart;           // 4.2 MB < 16.8 MB; consumed by reduce_bs before phase2 writes hstart

  // weight prep
  transpose_cast<<<dim3((2*DI)/32, DMODEL/32), dim3(32,8), 0, stream>>>(W_in, WinT, DMODEL, 2*DI);
  transpose_cast<<<dim3(DI/32, DI/32), dim3(32,8), 0, stream>>>(W_dt, WdtT, DI, DI);
  transpose_cast<<<dim3(DMODEL/32, DI/32), dim3(32,8), 0, stream>>>(W_out, WoutT, DI, DMODEL);
  transpose_cast<<<dim3(1, DI/32), dim3(32,8), 0, stream>>>(W_x, WxT, DI, DST);
  prep_a2<<<(DI*DST + 255)/256, 256, 0, stream>>>(A_log, A2n, DI*DST);
  hipMemsetAsync(flag, 0, 4, stream);
  check_a2<<<DI/256, 256, 0, stream>>>(A2n, flag);

  for (int b = 0; b < NBATCH; ++b) {
    const float* xb = x + (size_t)b*LSEQ*DMODEL;
    float* outb = out + (size_t)b*LSEQ*DMODEL;
    // cast x -> bf16
    cast_f32_bf16<<<(LSEQ*DMODEL/4 + 255)/256, 256, 0, stream>>>(xb, xbf, LSEQ*DMODEL/4);
    // xz = x @ W_in ; xs raw bf16 + silu(z) bf16  (128x256, frag-dbuf)
    gemm8<128,256,2,4,0><<<dim3(4096/256, 4096/128), 512, 0, stream>>>(xbf, WinT, DMODEL, xsr, szb, nullptr);
    // depthwise conv + silu -> bf16
    conv_silu<<<(LSEQ/8)*DI/256, 256, 0, stream>>>(xsr, convw, convb, xsb);
    // dt = softplus(xs @ W_dt + b_dt) -> bf16  (128x256, frag-dbuf)
    gemm8<128,256,2,4,1><<<dim3(2048/256, 4096/128), 512, 0, stream>>>(xsb, WdtT, DI, dtb, nullptr, b_dt);
    // Bs = xs @ W_x via split-K partials + reduce -> f32
    gemm_bs<<<dim3(KSPLIT, LSEQ/128), 256, 0, stream>>>(xsb, WxT, BsP);
    reduce_bs<<<(LSEQ*DST/4 + 255)/256, 256, 0, stream>>>(BsP, BsB, LSEQ*DST/4);
    // chunked scan (hlocal lives in xsr's storage; SoA carry layout)
    scan_phase1<<<dim3(DI/256, NCHUNK), 256, 0, stream>>>(dtb, BsB, A2n, hlocal, sumdt, flag);
    scan_phase2<<<(DI*DST)/256, 256, 0, stream>>>(hlocal, sumdt, A2n, hstart);
    scan_phase3<<<dim3(DI/256, NCHUNK), 256, 0, stream>>>(dtb, BsB, A2n, hstart, xsb, szb, Dvec, ybf, flag);
    // out = y @ W_out (f32)  (128x128, frag-dbuf)
    gemm8<128,128,2,4,2><<<dim3(1024/128, 4096/128), 512, 0, stream>>>(ybf, WoutT, DI, outb, nullptr, nullptr);
  }
}

// Round 12
// 792.213 us; speedup vs baseline: 1.0180x; 1.0180x over previous
//
#include <hip/hip_runtime.h>

typedef __attribute__((ext_vector_type(8))) short bf16x8;
typedef __attribute__((ext_vector_type(4))) float f32x4;
typedef __attribute__((ext_vector_type(16))) float f32x16;

#define NBATCH 4
#define LSEQ   4096
#define DMODEL 1024
#define DI     2048
#define DST    16
#define NCHUNK 128
#define CLEN   (LSEQ/NCHUNK)   // 32
#define KSPLIT 8               // split-K factor for Bs GEMM

// ---------------- helpers ----------------
__device__ __forceinline__ ushort f2bf(float x){
  union { float f; unsigned u; } v; v.f = x;
  unsigned r = v.u + 0x7FFFu + ((v.u >> 16) & 1u);
  return (ushort)(r >> 16);
}
__device__ __forceinline__ float bf2f(ushort h){
  union { unsigned u; float f; } v; v.u = ((unsigned)h) << 16;
  return v.f;
}
__device__ __forceinline__ float fexp2(float x){
  float r; asm("v_exp_f32 %0, %1" : "=v"(r) : "v"(x)); return r;
}
__device__ __forceinline__ float fsilu(float x){
  return x * __builtin_amdgcn_rcpf(1.f + __expf(-x));
}
__device__ __forceinline__ void gld_lds16(const ushort* g, ushort* l){
  __builtin_amdgcn_global_load_lds(
    (const __attribute__((address_space(1))) unsigned int*)g,
    (__attribute__((address_space(3))) unsigned int*)l, 16, 0, 0);
}

// ---------------- elementwise cast f32 -> bf16 (x4 vectorized) ----------------
__global__ void cast_f32_bf16(const float* __restrict__ in, ushort* __restrict__ out, int n4){
  int i = blockIdx.x*blockDim.x + threadIdx.x;
  if (i >= n4) return;
  float4 v = ((const float4*)in)[i];
  ushort4 o; o.x=f2bf(v.x); o.y=f2bf(v.y); o.z=f2bf(v.z); o.w=f2bf(v.w);
  ((ushort4*)out)[i] = o;
}

// ---------------- transpose + cast: out[c][r] = bf16(in[r][c]) ----------------
__global__ void transpose_cast(const float* __restrict__ in, ushort* __restrict__ out, int R, int C){
  __shared__ float tile[32][33];
  int c0 = blockIdx.x*32, r0 = blockIdx.y*32;
  int tx = threadIdx.x, ty = threadIdx.y;   // 32 x 8
  #pragma unroll
  for (int i=0;i<4;i++){
    int r = r0 + ty + i*8;
    if (r < R && (c0+tx) < C) tile[ty+i*8][tx] = in[(size_t)r*C + c0 + tx];
  }
  __syncthreads();
  #pragma unroll
  for (int i=0;i<4;i++){
    int c = c0 + ty + i*8;
    if (c < C && (r0+tx) < R) out[(size_t)c*R + r0 + tx] = f2bf(tile[tx][ty+i*8]);
  }
}

// A2n = -exp(A_log) * log2(e)
__global__ void prep_a2(const float* __restrict__ A_log, float* __restrict__ A2n, int n){
  int i = blockIdx.x*blockDim.x + threadIdx.x;
  if (i < n) A2n[i] = -expf(A_log[i]) * 1.4426950408889634f;
}

// Check whether a2[c][s] == (s+1)*a2[c][0] for all channels (enables 1-exp scan path).
__global__ void check_a2(const float* __restrict__ A2n, int* __restrict__ flag){
  int c = blockIdx.x*blockDim.x + threadIdx.x;
  if (c >= DI) return;
  const float* a = A2n + (size_t)c*DST;
  float a0 = a[0];
  int bad = 0;
  #pragma unroll
  for (int s=1;s<DST;s++){
    float want = (float)(s+1)*a0;
    if (fabsf(a[s] - want) > 1e-4f*fabsf(want) + 1e-12f) bad = 1;
  }
  if (bad) atomicOr(flag, 1);
}

// ======== pipelined bf16 MFMA GEMM, 32x32x16 shape, B in N x K layout ========
// R5/R10-proven skeleton: 512 threads = 8 waves, BK=32, DEPTH=4 LDS buffers,
// stage(t+3) lookahead, counted vmcnt(2L), one barrier per tile.
// K-loop uses v_mfma_f32_32x32x16_bf16: half the MFMA instructions at a 15%
// faster pipe rate (m119: 2495 vs 2075 TF) for the same fragment traffic.
// A/B frag: row=lane&31, k=(lane>>5)*8+j. C/D: col=lane&31,
// row=(reg&3)+8*(reg>>2)+4*(lane>>5)  [guide m74/m101 verified].
template<int BM, int BN, int WM, int WN, int MODE>
__global__ __launch_bounds__(512, 2)
void gemm8(const ushort* __restrict__ A, const ushort* __restrict__ Bm, const int K,
           void* __restrict__ out0, void* __restrict__ out1, const float* __restrict__ bias)
{
  constexpr int TM = BM/WM, TN = BN/WN;          // per-wave tile (rows x cols)
  constexpr int MR = TM/32, NR = TN/32;          // 32x32 fragment repeats
  constexpr int AI = BM/128, BI = BN/128;        // gld_lds instrs per wave per tile
  constexpr int L  = AI + BI;
  constexpr int DEPTH = 4, LA = DEPTH-1;
  constexpr int SA   = BM*32;                    // A-tile ushorts
  constexpr int SBUF = (BM+BN)*32;               // per-buffer ushorts
  __shared__ __align__(16) ushort lds[DEPTH*SBUF];

  const int tid = threadIdx.x;
  const int w = tid >> 6, lane = tid & 63;
  const int lr = lane & 31, lh = lane >> 5;      // frag row / k-half
  const int wm = w / WN, wn = w % WN;
  const int bn = blockIdx.x, bm = blockIdx.y;
  const int nt = K >> 5;

  const size_t Abase = (size_t)bm*BM*K;
  const size_t Bbase = (size_t)bn*BN*K;

  f32x16 acc[MR][NR];
  #pragma unroll
  for (int i=0;i<MR;i++)
    #pragma unroll
    for (int j=0;j<NR;j++)
      #pragma unroll
      for (int e=0;e<16;e++) acc[i][j][e] = 0.f;

  auto stage = [&](int t, int bufidx){
    ushort* buf = &lds[(size_t)bufidx*SBUF];
    const int k0 = t*32;
    #pragma unroll
    for (int i=0;i<AI;i++){
      int slot = (w*AI+i)*64 + lane;
      int row  = slot >> 2;
      int s16  = (lane&3) ^ ((row>>1)&3);
      gld_lds16(A + Abase + (size_t)row*K + k0 + s16*8, buf + (w*AI+i)*512);
    }
    #pragma unroll
    for (int i=0;i<BI;i++){
      int slot = (w*BI+i)*64 + lane;
      int row  = slot >> 2;
      int s16  = (lane&3) ^ ((row>>1)&3);
      gld_lds16(Bm + Bbase + (size_t)row*K + k0 + s16*8, buf + SA + (w*BI+i)*512);
    }
  };

  #pragma unroll
  for (int i=0;i<LA;i++) stage(i, i);
  __builtin_amdgcn_s_waitcnt(0xF70 | ((LA-1)*L));
  __builtin_amdgcn_sched_barrier(0);
  __builtin_amdgcn_s_barrier();

  int rb = 0;
  int sb = LA % DEPTH;
  for (int t=0; t<nt; ++t){
    if (t+LA < nt) stage(t+LA, sb);

    const ushort* bufc = &lds[(size_t)rb*SBUF];
    bf16x8 af[MR][2], bfv[NR][2];
    #pragma unroll
    for (int kki=0;kki<2;kki++){
      int c = kki*2 + lh;                        // global 16B k-chunk within row
      #pragma unroll
      for (int ni=0;ni<NR;ni++){
        int row = wn*TN + ni*32 + lr;
        bfv[ni][kki] = *(const bf16x8*)&bufc[SA + row*32 + ((c ^ ((row>>1)&3))<<3)];
      }
      #pragma unroll
      for (int mi=0;mi<MR;mi++){
        int row = wm*TM + mi*32 + lr;
        af[mi][kki] = *(const bf16x8*)&bufc[row*32 + ((c ^ ((row>>1)&3))<<3)];
      }
    }
    __builtin_amdgcn_s_setprio(1);
    #pragma unroll
    for (int kki=0;kki<2;kki++)
      #pragma unroll
      for (int mi=0;mi<MR;mi++)
        #pragma unroll
        for (int ni=0;ni<NR;ni++)
          acc[mi][ni] = __builtin_amdgcn_mfma_f32_32x32x16_bf16(af[mi][kki], bfv[ni][kki], acc[mi][ni], 0, 0, 0);
    __builtin_amdgcn_s_setprio(0);

    rb = (rb+1 == DEPTH) ? 0 : rb+1;
    sb = (sb+1 == DEPTH) ? 0 : sb+1;

    if (t+1 < nt){
      int k = nt-2-t; if (k > DEPTH-2) k = DEPTH-2;
      if (k <= 0) __builtin_amdgcn_s_waitcnt(0xF70);
      else if (k == 1) __builtin_amdgcn_s_waitcnt(0xF70 | (1*L));
      else             __builtin_amdgcn_s_waitcnt(0xF70 | (2*L));
      __builtin_amdgcn_sched_barrier(0);
      __builtin_amdgcn_s_barrier();
    }
  }

  const int row0 = bm*BM + wm*TM;
  const int col0 = bn*BN + wn*TN;
  #pragma unroll
  for (int mi=0;mi<MR;mi++){
    #pragma unroll
    for (int ni=0;ni<NR;ni++){
      int c = col0 + ni*32 + lr;
      #pragma unroll
      for (int j=0;j<16;j++){
        int r = row0 + mi*32 + (j&3) + ((j>>2)<<3) + (lh<<2);
        float v = acc[mi][ni][j];
        size_t rr = (size_t)r;
        if (MODE==0){
          if (c < 2048) ((ushort*)out0)[rr*2048 + c] = f2bf(v);
          else          ((ushort*)out1)[rr*2048 + (c-2048)] = f2bf(fsilu(v));
        } else if (MODE==1){
          float u = v + bias[c];
          float sp = (u > 15.f) ? u : logf(1.f + __expf(u));
          ((ushort*)out0)[rr*2048 + c] = f2bf(sp);
        } else if (MODE==2){
          ((float*)out0)[rr*1024 + c] = v;
        }
      }
    }
  }
}

// ---------------- split-K skinny GEMM for Bs: 4096x16x2048, partials over K ----------------
__global__ __launch_bounds__(256, 2)
void gemm_bs(const ushort* __restrict__ A, const ushort* __restrict__ WxT,
             float* __restrict__ partial)
{
  __shared__ __align__(16) ushort As[128*32];
  __shared__ __align__(16) ushort Bs[16*32];
  const int tid = threadIdx.x;
  const int wave = tid >> 6, lane = tid & 63;
  const int kc = blockIdx.x, bm = blockIdx.y;
  const int lm = lane & 15, kk = (lane >> 4) * 8;
  const int KC = DI / KSPLIT;    // 256
  f32x4 acc[2];
  acc[0] = (f32x4){0.f,0.f,0.f,0.f};
  acc[1] = (f32x4){0.f,0.f,0.f,0.f};
  const size_t Abase = (size_t)bm*128*DI;
  for (int k0 = kc*KC; k0 < (kc+1)*KC; k0 += 32) {
    __syncthreads();
    #pragma unroll
    for (int j=0;j<2;j++){
      int f = j*2048 + tid*8;
      gld_lds16(A + Abase + (size_t)(f>>5)*DI + k0 + (f&31), &As[j*2048 + wave*512]);
    }
    if (wave == 0){
      int f = lane*8;            // 16 rows x 32 cols
      gld_lds16(WxT + (size_t)(f>>5)*DI + k0 + (f&31), &Bs[0]);
    }
    __syncthreads();
    bf16x8 bfv = *(const bf16x8*)&Bs[lm*32 + kk];
    #pragma unroll
    for (int mi=0;mi<2;mi++){
      bf16x8 af = *(const bf16x8*)&As[(wave*32+mi*16+lm)*32 + kk];
      acc[mi] = __builtin_amdgcn_mfma_f32_16x16x32_bf16(af, bfv, acc[mi], 0, 0, 0);
    }
  }
  float* outp = partial + (size_t)kc*LSEQ*DST;
  #pragma unroll
  for (int mi=0;mi<2;mi++){
    int rbase = bm*128 + wave*32 + mi*16 + (lane>>4)*4;
    #pragma unroll
    for (int j=0;j<4;j++)
      outp[(size_t)(rbase+j)*DST + lm] = acc[mi][j];
  }
}

// sum the KSPLIT partials -> BsB
__global__ void reduce_bs(const float* __restrict__ partial, float* __restrict__ out, int n4){
  int i = blockIdx.x*blockDim.x + threadIdx.x;
  if (i >= n4) return;
  float4 s = ((const float4*)partial)[i];
  #pragma unroll
  for (int k=1;k<KSPLIT;k++){
    float4 v = ((const float4*)(partial + (size_t)k*LSEQ*DST))[i];
    s.x += v.x; s.y += v.y; s.z += v.z; s.w += v.w;
  }
  ((float4*)out)[i] = s;
}

// ---------------- depthwise causal conv K=4 + silu, bf16 in/out (one batch) ----------------
__global__ __launch_bounds__(256)
void conv_silu(const ushort* __restrict__ xs_raw, const float* __restrict__ w,
               const float* __restrict__ cb, ushort* __restrict__ out)
{
  int idx = blockIdx.x*256 + threadIdx.x;   // (LSEQ/8)*DI threads
  int c  = idx & (DI-1);
  int l8 = idx >> 11;                       // 0..511
  int l0 = l8*8;
  float w0=w[c*4+0], w1=w[c*4+1], w2=w[c*4+2], w3=w[c*4+3];
  float bias = cb[c];
  const ushort* base = xs_raw + c;
  float v[11];
  #pragma unroll
  for (int i=0;i<11;i++){
    int t = l0 - 3 + i;
    v[i] = (t >= 0) ? bf2f(base[(size_t)t*DI]) : 0.f;
  }
  ushort* ob = out + (size_t)l0*DI + c;
  #pragma unroll
  for (int i=0;i<8;i++){
    float acc = bias + v[i]*w0 + v[i+1]*w1 + v[i+2]*w2 + v[i+3]*w3;
    ob[(size_t)i*DI] = f2bf(fsilu(acc));
  }
}

// decay helpers: fast path builds g^(s+1) from one exp (valid when a2[s]=(s+1)*a2[0])
__device__ __forceinline__ void build_pw(float g, float* pw){
  pw[0]=g;        pw[1]=g*g;       pw[2]=pw[1]*g;    pw[3]=pw[1]*pw[1];
  pw[4]=pw[3]*g;  pw[5]=pw[3]*pw[1]; pw[6]=pw[3]*pw[2]; pw[7]=pw[3]*pw[3];
  pw[8]=pw[7]*g;  pw[9]=pw[7]*pw[1]; pw[10]=pw[7]*pw[2]; pw[11]=pw[7]*pw[3];
  pw[12]=pw[7]*pw[4]; pw[13]=pw[7]*pw[5]; pw[14]=pw[7]*pw[6]; pw[15]=pw[7]*pw[7];
}

// Carry tensors use SoA layout: hlocal/hstart[((ch*DST + s)*DI) + c]

// ---------------- scan phase 1: per-chunk local scan, h0=0 (one batch) ----------------
__global__ __launch_bounds__(256)
void scan_phase1(const ushort* __restrict__ dtb, const float* __restrict__ bsb,
                 const float* __restrict__ A2n, float* __restrict__ hlocal,
                 float* __restrict__ sumdt, const int* __restrict__ flagp)
{
  __shared__ __align__(16) float bs_s[CLEN][DST];
  const int c  = blockIdx.x*256 + threadIdx.x;
  const int ch = blockIdx.y;
  if (threadIdx.x < CLEN*DST/4)
    ((float4*)bs_s)[threadIdx.x] = ((const float4*)(bsb + (size_t)ch*CLEN*DST))[threadIdx.x];
  __syncthreads();
  float h[DST];
  #pragma unroll
  for (int s=0;s<DST;s++) h[s] = 0.f;
  float sdt = 0.f;
  const ushort* dtp = dtb + (size_t)ch*CLEN*DI + c;
  if (flagp[0] == 0){
    const float a0 = A2n[(size_t)c*DST];
    #pragma unroll 4
    for (int t=0;t<CLEN;t++){
      float d = bf2f(dtp[(size_t)t*DI]);
      sdt += d;
      float pw[DST];
      build_pw(fexp2(a0*d), pw);
      #pragma unroll
      for (int s=0;s<DST;s++) h[s] = fmaf(h[s], pw[s], bs_s[t][s]);
    }
  } else {
    float a2[DST];
    #pragma unroll
    for (int i=0;i<4;i++) *(float4*)&a2[i*4] = *(const float4*)&A2n[(size_t)c*DST + i*4];
    #pragma unroll 2
    for (int t=0;t<CLEN;t++){
      float d = bf2f(dtp[(size_t)t*DI]);
      sdt += d;
      #pragma unroll
      for (int s=0;s<DST;s++) h[s] = fmaf(h[s], fexp2(a2[s]*d), bs_s[t][s]);
    }
  }
  size_t o = (size_t)ch*DST*DI + c;
  #pragma unroll
  for (int s=0;s<DST;s++) hlocal[o + (size_t)s*DI] = h[s];
  sumdt[(size_t)ch*DI + c] = sdt;
}

// ---------------- scan phase 2: chunk-level prefix over NCHUNK chunks ----------------
__global__ void scan_phase2(const float* __restrict__ hlocal, const float* __restrict__ sumdt,
                            const float* __restrict__ A2n, float* __restrict__ hstart)
{
  int id = blockIdx.x*blockDim.x + threadIdx.x;   // DI*DST = 32768
  int c = id & (DI-1);
  int s = id >> 11;
  float a2 = A2n[(size_t)c*DST + s];
  float h = 0.f;
  for (int ch=0; ch<NCHUNK; ++ch){
    size_t o = ((size_t)ch*DST + s)*DI + c;
    hstart[o] = h;
    float sd = sumdt[(size_t)ch*DI + c];
    h = fmaf(h, fexp2(a2*sd), hlocal[o]);
  }
}

// ---------------- scan phase 3: replay with carry, emit y*silu(z) bf16 ----------------
__global__ __launch_bounds__(256)
void scan_phase3(const ushort* __restrict__ dtb, const float* __restrict__ bsb,
                 const float* __restrict__ A2n, const float* __restrict__ hstart,
                 const ushort* __restrict__ xsbf, const ushort* __restrict__ szb,
                 const float* __restrict__ Dv, ushort* __restrict__ ybf,
                 const int* __restrict__ flagp)
{
  __shared__ __align__(16) float bs_s[CLEN][DST];
  const int c  = blockIdx.x*256 + threadIdx.x;
  const int ch = blockIdx.y;
  if (threadIdx.x < CLEN*DST/4)
    ((float4*)bs_s)[threadIdx.x] = ((const float4*)(bsb + (size_t)ch*CLEN*DST))[threadIdx.x];
  __syncthreads();
  float h[DST];
  size_t ho = (size_t)ch*DST*DI + c;
  #pragma unroll
  for (int s=0;s<DST;s++) h[s] = hstart[ho + (size_t)s*DI];
  const float Dc = Dv[c];
  const size_t base = (size_t)ch*CLEN*DI + c;
  const ushort* dtp = dtb + base;
  const ushort* xp  = xsbf + base;
  const ushort* szp = szb + base;
  ushort* yp = ybf + base;
  if (flagp[0] == 0){
    const float a0 = A2n[(size_t)c*DST];
    #pragma unroll 4
    for (int t=0;t<CLEN;t++){
      float d = bf2f(dtp[(size_t)t*DI]);
      float pw[DST];
      build_pw(fexp2(a0*d), pw);
      #pragma unroll
      for (int s=0;s<DST;s++) h[s] = fmaf(h[s], pw[s], bs_s[t][s]);
      float ysum = ((h[0]+h[1])+(h[2]+h[3])) + ((h[4]+h[5])+(h[6]+h[7]))
                 + ((h[8]+h[9])+(h[10]+h[11])) + ((h[12]+h[13])+(h[14]+h[15]));
      float xv = bf2f(xp[(size_t)t*DI]);
      float yv = fmaf(Dc, xv, ysum);
      yp[(size_t)t*DI] = f2bf(yv * bf2f(szp[(size_t)t*DI]));
    }
  } else {
    float a2[DST];
    #pragma unroll
    for (int i=0;i<4;i++) *(float4*)&a2[i*4] = *(const float4*)&A2n[(size_t)c*DST + i*4];
    #pragma unroll 2
    for (int t=0;t<CLEN;t++){
      float d = bf2f(dtp[(size_t)t*DI]);
      #pragma unroll
      for (int s=0;s<DST;s++) h[s] = fmaf(h[s], fexp2(a2[s]*d), bs_s[t][s]);
      float ysum = ((h[0]+h[1])+(h[2]+h[3])) + ((h[4]+h[5])+(h[6]+h[7]))
                 + ((h[8]+h[9])+(h[10]+h[11])) + ((h[12]+h[13])+(h[14]+h[15]));
      float xv = bf2f(xp[(size_t)t*DI]);
      float yv = fmaf(Dc, xv, ysum);
      yp[(size_t)t*DI] = f2bf(yv * bf2f(szp[(size_t)t*DI]));
    }
  }
}

// ---------------- launch ----------------
extern "C" void kernel_launch(void* const* d_in, const int* in_sizes, int n_in,
                              void* d_out, int out_size, void* d_ws, size_t ws_size,
                              hipStream_t stream)
{
  if (n_in < 10) return;
  const float* x     = (const float*)d_in[0];
  const float* W_in  = (const float*)d_in[1];
  const float* convw = (const float*)d_in[2];
  const float* convb = (const float*)d_in[3];
  const float* A_log = (const float*)d_in[4];
  const float* Dvec  = (const float*)d_in[5];
  const float* W_x   = (const float*)d_in[6];
  const float* W_dt  = (const float*)d_in[7];
  const float* b_dt  = (const float*)d_in[8];
  const float* W_out = (const float*)d_in[9];
  float* out = (float*)d_out;

  char* p = (char*)d_ws;
  auto alloc = [&](size_t n){ char* r = p; p += (n + 255) & ~(size_t)255; return r; };
  // weights (once)
  ushort* WinT   = (ushort*)alloc((size_t)(2*DI)*DMODEL*2);   //  8.4 MB
  ushort* WdtT   = (ushort*)alloc((size_t)DI*DI*2);           //  8.4 MB
  ushort* WoutT  = (ushort*)alloc((size_t)DMODEL*DI*2);       //  4.2 MB
  ushort* WxT    = (ushort*)alloc((size_t)DST*DI*2);          //  64 KB
  float*  A2n    = (float*)alloc((size_t)DI*DST*4);           //  0.1 MB
  int*    flag   = (int*)alloc(256);
  // per-batch activations (reused across the 4 batches)
  ushort* xbf    = (ushort*)alloc((size_t)LSEQ*DMODEL*2);     //  8.4 MB
  ushort* xsr    = (ushort*)alloc((size_t)LSEQ*DI*2);         // 16.8 MB raw xs; dead after conv -> reused as hlocal
  ushort* szb    = (ushort*)alloc((size_t)LSEQ*DI*2);         // 16.8 MB silu(z)
  ushort* xsb    = (ushort*)alloc((size_t)LSEQ*DI*2);         // 16.8 MB conv+silu
  ushort* dtb    = (ushort*)alloc((size_t)LSEQ*DI*2);         // 16.8 MB dt
  ushort* ybf    = (ushort*)alloc((size_t)LSEQ*DI*2);         // 16.8 MB y
  float*  BsB    = (float*)alloc((size_t)LSEQ*DST*4);         //  0.3 MB
  float*  hstart = (float*)alloc((size_t)NCHUNK*DI*DST*4);    // 16.8 MB (aliased by BsP pre-scan)
  float*  sumdt  = (float*)alloc((size_t)NCHUNK*DI*4);        //  1.0 MB
  if ((size_t)(p - (char*)d_ws) > ws_size) return;   // ws too small: no OOB
  float* hlocal = (float*)xsr;   // 16.8 MB == xsr size; xsr dead after conv,
                                 // hlocal dead after phase2 (before next batch's gemm0 rewrites xsr)
  float* BsP = hstart;           // 4.2 MB < 16.8 MB; consumed by reduce_bs before phase2 writes hstart

  // weight prep
  transpose_cast<<<dim3((2*DI)/32, DMODEL/32), dim3(32,8), 0, stream>>>(W_in, WinT, DMODEL, 2*DI);
  transpose_cast<<<dim3(DI/32, DI/32), dim3(32,8), 0, stream>>>(W_dt, WdtT, DI, DI);
  transpose_cast<<<dim3(DMODEL/32, DI/32), dim3(32,8), 0, stream>>>(W_out, WoutT, DI, DMODEL);
  transpose_cast<<<dim3(1, DI/32), dim3(32,8), 0, stream>>>(W_x, WxT, DI, DST);
  prep_a2<<<(DI*DST + 255)/256, 256, 0, stream>>>(A_log, A2n, DI*DST);
  hipMemsetAsync(flag, 0, 4, stream);
  check_a2<<<DI/256, 256, 0, stream>>>(A2n, flag);

  for (int b = 0; b < NBATCH; ++b) {
    const float* xb = x + (size_t)b*LSEQ*DMODEL;
    float* outb = out + (size_t)b*LSEQ*DMODEL;
    // cast x -> bf16
    cast_f32_bf16<<<(LSEQ*DMODEL/4 + 255)/256, 256, 0, stream>>>(xb, xbf, LSEQ*DMODEL/4);
    // xz = x @ W_in ; xs raw bf16 + silu(z) bf16  (256^2 tile)
    gemm8<256,256,2,4,0><<<dim3(4096/256, 4096/256), 512, 0, stream>>>(xbf, WinT, DMODEL, xsr, szb, nullptr);
    // depthwise conv + silu -> bf16
    conv_silu<<<(LSEQ/8)*DI/256, 256, 0, stream>>>(xsr, convw, convb, xsb);
    // dt = softplus(xs @ W_dt + b_dt) -> bf16  (128x256)
    gemm8<128,256,2,4,1><<<dim3(2048/256, 4096/128), 512, 0, stream>>>(xsb, WdtT, DI, dtb, nullptr, b_dt);
    // Bs = xs @ W_x via split-K partials + reduce -> f32
    gemm_bs<<<dim3(KSPLIT, LSEQ/128), 256, 0, stream>>>(xsb, WxT, BsP);
    reduce_bs<<<(LSEQ*DST/4 + 255)/256, 256, 0, stream>>>(BsP, BsB, LSEQ*DST/4);
    // chunked scan (hlocal lives in xsr's storage; SoA carry layout)
    scan_phase1<<<dim3(DI/256, NCHUNK), 256, 0, stream>>>(dtb, BsB, A2n, hlocal, sumdt, flag);
    scan_phase2<<<(DI*DST)/256, 256, 0, stream>>>(hlocal, sumdt, A2n, hstart);
    scan_phase3<<<dim3(DI/256, NCHUNK), 256, 0, stream>>>(dtb, BsB, A2n, hstart, xsb, szb, Dvec, ybf, flag);
    // out = y @ W_out (f32)  (128x128)
    gemm8<128,128,2,4,2><<<dim3(1024/128, 4096/128), 512, 0, stream>>>(ybf, WoutT, DI, outb, nullptr, nullptr);
  }
}

// Round 13
// 729.816 us; speedup vs baseline: 1.1051x; 1.0855x over previous
//
#include <hip/hip_runtime.h>

typedef __attribute__((ext_vector_type(8))) short bf16x8;
typedef __attribute__((ext_vector_type(4))) float f32x4;

#define NBATCH 4
#define LSEQ   4096
#define DMODEL 1024
#define DI     2048
#define DST    16
#define NCHUNK 128
#define CLEN   (LSEQ/NCHUNK)   // 32
#define KSPLIT 8               // split-K factor for Bs GEMM

// ---------------- helpers ----------------
__device__ __forceinline__ ushort f2bf(float x){
  union { float f; unsigned u; } v; v.f = x;
  unsigned r = v.u + 0x7FFFu + ((v.u >> 16) & 1u);
  return (ushort)(r >> 16);
}
__device__ __forceinline__ float bf2f(ushort h){
  union { unsigned u; float f; } v; v.u = ((unsigned)h) << 16;
  return v.f;
}
__device__ __forceinline__ float fexp2(float x){
  float r; asm("v_exp_f32 %0, %1" : "=v"(r) : "v"(x)); return r;
}
__device__ __forceinline__ float fsilu(float x){
  return x * __builtin_amdgcn_rcpf(1.f + __expf(-x));
}
__device__ __forceinline__ void gld_lds16(const ushort* g, ushort* l){
  __builtin_amdgcn_global_load_lds(
    (const __attribute__((address_space(1))) unsigned int*)g,
    (__attribute__((address_space(3))) unsigned int*)l, 16, 0, 0);
}

// ---------------- elementwise cast f32 -> bf16 (x4 vectorized) ----------------
__global__ void cast_f32_bf16(const float* __restrict__ in, ushort* __restrict__ out, int n4){
  int i = blockIdx.x*blockDim.x + threadIdx.x;
  if (i >= n4) return;
  float4 v = ((const float4*)in)[i];
  ushort4 o; o.x=f2bf(v.x); o.y=f2bf(v.y); o.z=f2bf(v.z); o.w=f2bf(v.w);
  ((ushort4*)out)[i] = o;
}

// ---------------- transpose + cast: out[c][r] = bf16(in[r][c]) ----------------
__global__ void transpose_cast(const float* __restrict__ in, ushort* __restrict__ out, int R, int C){
  __shared__ float tile[32][33];
  int c0 = blockIdx.x*32, r0 = blockIdx.y*32;
  int tx = threadIdx.x, ty = threadIdx.y;   // 32 x 8
  #pragma unroll
  for (int i=0;i<4;i++){
    int r = r0 + ty + i*8;
    if (r < R && (c0+tx) < C) tile[ty+i*8][tx] = in[(size_t)r*C + c0 + tx];
  }
  __syncthreads();
  #pragma unroll
  for (int i=0;i<4;i++){
    int c = c0 + ty + i*8;
    if (c < C && (r0+tx) < R) out[(size_t)c*R + r0 + tx] = f2bf(tile[tx][ty+i*8]);
  }
}

// A2n = -exp(A_log) * log2(e)
__global__ void prep_a2(const float* __restrict__ A_log, float* __restrict__ A2n, int n){
  int i = blockIdx.x*blockDim.x + threadIdx.x;
  if (i < n) A2n[i] = -expf(A_log[i]) * 1.4426950408889634f;
}

// Check whether a2[c][s] == (s+1)*a2[c][0] for all channels (enables 1-exp scan path).
__global__ void check_a2(const float* __restrict__ A2n, int* __restrict__ flag){
  int c = blockIdx.x*blockDim.x + threadIdx.x;
  if (c >= DI) return;
  const float* a = A2n + (size_t)c*DST;
  float a0 = a[0];
  int bad = 0;
  #pragma unroll
  for (int s=1;s<DST;s++){
    float want = (float)(s+1)*a0;
    if (fabsf(a[s] - want) > 1e-4f*fabsf(want) + 1e-12f) bad = 1;
  }
  if (bad) atomicOr(flag, 1);
}

// ======== pipelined bf16 MFMA GEMM (R10 schedule + strength-reduced addressing) ========
// 512 threads = 8 waves, BK=32, 4 LDS buffers, stage(t+3) lookahead, counted vmcnt,
// one barrier per tile (R5/R10-proven). NEW: all addresses hoisted out of the K-loop:
// - frag-read lane address per buffer per operand (swizzle bits invariant across mi/ni)
// - stage global pointers advanced by +32/tile
// - K-loop unrolled x4 so buffer indices are compile-time (no dynamic indexing)
template<int BM, int BN, int WM, int WN, int MODE>
__global__ __launch_bounds__(512, 2)
void gemm8(const ushort* __restrict__ A, const ushort* __restrict__ Bm, const int K,
           void* __restrict__ out0, void* __restrict__ out1, const float* __restrict__ bias)
{
  constexpr int TM = BM/WM, TN = BN/WN;
  constexpr int MR = TM/16, NR = TN/16;
  constexpr int AI = BM/128, BI = BN/128;
  constexpr int L  = AI + BI;
  constexpr int SA   = BM*32;
  constexpr int SBUF = (BM+BN)*32;
  __shared__ __align__(16) ushort lds[4*SBUF];

  const int tid = threadIdx.x;
  const int w = tid >> 6, lane = tid & 63;
  const int lm = lane & 15, lq = lane >> 4;
  const int wm = w / WN, wn = w % WN;
  const int bn = blockIdx.x, bm = blockIdx.y;
  const int nt = K >> 5;                         // 32 or 64: divisible by 4

  f32x4 acc[MR][NR];
  #pragma unroll
  for (int i=0;i<MR;i++)
    #pragma unroll
    for (int j=0;j<NR;j++) acc[i][j] = (f32x4){0.f,0.f,0.f,0.f};

  // ---- hoisted frag-read lane addresses (one per buffer per operand) ----
  // addr(mi) = aA[s] + mi*512 ushorts: swizzle bits invariant across mi since
  // ((row+16*mi)>>1)&3 == (row>>1)&3.
  const int rowA0 = wm*TM + lm;
  const int rowB0 = wn*TN + lm;
  const int offA = rowA0*32 + ((lq ^ ((rowA0>>1)&3))<<3);
  const int offB = SA + rowB0*32 + ((lq ^ ((rowB0>>1)&3))<<3);
  const ushort* aA[4] = { &lds[0*SBUF+offA], &lds[1*SBUF+offA], &lds[2*SBUF+offA], &lds[3*SBUF+offA] };
  const ushort* aB[4] = { &lds[0*SBUF+offB], &lds[1*SBUF+offB], &lds[2*SBUF+offB], &lds[3*SBUF+offB] };

  // ---- hoisted stage source pointers (advance +32 per K-tile) ----
  const ushort* pA[AI]; const ushort* pB[BI];
  #pragma unroll
  for (int i=0;i<AI;i++){
    int slot = (w*AI+i)*64 + lane;
    int row  = slot >> 2;
    int s16  = (lane&3) ^ ((row>>1)&3);
    pA[i] = A + (size_t)bm*BM*K + (size_t)row*K + s16*8;
  }
  #pragma unroll
  for (int i=0;i<BI;i++){
    int slot = (w*BI+i)*64 + lane;
    int row  = slot >> 2;
    int s16  = (lane&3) ^ ((row>>1)&3);
    pB[i] = Bm + (size_t)bn*BN*K + (size_t)row*K + s16*8;
  }

#define STAGE(S) {                                                              \
    _Pragma("unroll")                                                           \
    for (int i=0;i<AI;i++) gld_lds16(pA[i], &lds[(S)*SBUF + (w*AI+i)*512]);     \
    _Pragma("unroll")                                                           \
    for (int i=0;i<BI;i++) gld_lds16(pB[i], &lds[(S)*SBUF + SA + (w*BI+i)*512]);\
  }
#define ADV() {                                                                 \
    _Pragma("unroll") for (int i=0;i<AI;i++) pA[i] += 32;                       \
    _Pragma("unroll") for (int i=0;i<BI;i++) pB[i] += 32;                       \
  }
#define SLOT(T, CS, SS) {                                                       \
    if ((T)+3 < nt) { STAGE(SS); }                                              \
    ADV();                                                                      \
    bf16x8 af[MR], bfv[NR];                                                     \
    _Pragma("unroll")                                                           \
    for (int ni=0;ni<NR;ni++) bfv[ni] = *(const bf16x8*)(aB[CS] + ni*512);      \
    _Pragma("unroll")                                                           \
    for (int mi=0;mi<MR;mi++) af[mi]  = *(const bf16x8*)(aA[CS] + mi*512);      \
    __builtin_amdgcn_s_setprio(1);                                              \
    _Pragma("unroll")                                                           \
    for (int mi=0;mi<MR;mi++)                                                   \
      _Pragma("unroll")                                                         \
      for (int ni=0;ni<NR;ni++)                                                 \
        acc[mi][ni] = __builtin_amdgcn_mfma_f32_16x16x32_bf16(af[mi], bfv[ni], acc[mi][ni], 0, 0, 0); \
    __builtin_amdgcn_s_setprio(0);                                              \
    if ((T)+1 < nt){                                                            \
      int kk2 = nt-2-(T); if (kk2 > 2) kk2 = 2;                                 \
      if (kk2 <= 0)      __builtin_amdgcn_s_waitcnt(0xF70);                     \
      else if (kk2 == 1) __builtin_amdgcn_s_waitcnt(0xF70 | L);                 \
      else               __builtin_amdgcn_s_waitcnt(0xF70 | (2*L));             \
      __builtin_amdgcn_sched_barrier(0);                                        \
      __builtin_amdgcn_s_barrier();                                             \
    }                                                                           \
  }

  // prologue: 3 tiles in flight, wait so tile 0 landed (leave 2L outstanding)
  STAGE(0); ADV(); STAGE(1); ADV(); STAGE(2); ADV();
  __builtin_amdgcn_s_waitcnt(0xF70 | (2*L));
  __builtin_amdgcn_sched_barrier(0);
  __builtin_amdgcn_s_barrier();

  for (int t=0; t<nt; t+=4){
    SLOT(t+0, 0, 3);
    SLOT(t+1, 1, 0);
    SLOT(t+2, 2, 1);
    SLOT(t+3, 3, 2);
  }
#undef SLOT
#undef ADV
#undef STAGE

  const int row0 = bm*BM + wm*TM;
  const int col0 = bn*BN + wn*TN;
  #pragma unroll
  for (int mi=0;mi<MR;mi++){
    #pragma unroll
    for (int ni=0;ni<NR;ni++){
      int c = col0 + ni*16 + lm;
      int rbase = row0 + mi*16 + lq*4;
      #pragma unroll
      for (int j=0;j<4;j++){
        float v = acc[mi][ni][j];
        size_t rr = (size_t)(rbase + j);
        if (MODE==0){
          if (c < 2048) ((ushort*)out0)[rr*2048 + c] = f2bf(v);
          else          ((ushort*)out1)[rr*2048 + (c-2048)] = f2bf(fsilu(v));
        } else if (MODE==1){
          float u = v + bias[c];
          float sp = (u > 15.f) ? u : logf(1.f + __expf(u));
          ((ushort*)out0)[rr*2048 + c] = f2bf(sp);
        } else if (MODE==2){
          ((float*)out0)[rr*1024 + c] = v;
        }
      }
    }
  }
}

// ---------------- split-K skinny GEMM for Bs: 4096x16x2048, partials over K ----------------
__global__ __launch_bounds__(256, 2)
void gemm_bs(const ushort* __restrict__ A, const ushort* __restrict__ WxT,
             float* __restrict__ partial)
{
  __shared__ __align__(16) ushort As[128*32];
  __shared__ __align__(16) ushort Bs[16*32];
  const int tid = threadIdx.x;
  const int wave = tid >> 6, lane = tid & 63;
  const int kc = blockIdx.x, bm = blockIdx.y;
  const int lm = lane & 15, kk = (lane >> 4) * 8;
  const int KC = DI / KSPLIT;    // 256
  f32x4 acc[2];
  acc[0] = (f32x4){0.f,0.f,0.f,0.f};
  acc[1] = (f32x4){0.f,0.f,0.f,0.f};
  const size_t Abase = (size_t)bm*128*DI;
  for (int k0 = kc*KC; k0 < (kc+1)*KC; k0 += 32) {
    __syncthreads();
    #pragma unroll
    for (int j=0;j<2;j++){
      int f = j*2048 + tid*8;
      gld_lds16(A + Abase + (size_t)(f>>5)*DI + k0 + (f&31), &As[j*2048 + wave*512]);
    }
    if (wave == 0){
      int f = lane*8;            // 16 rows x 32 cols
      gld_lds16(WxT + (size_t)(f>>5)*DI + k0 + (f&31), &Bs[0]);
    }
    __syncthreads();
    bf16x8 bfv = *(const bf16x8*)&Bs[lm*32 + kk];
    #pragma unroll
    for (int mi=0;mi<2;mi++){
      bf16x8 af = *(const bf16x8*)&As[(wave*32+mi*16+lm)*32 + kk];
      acc[mi] = __builtin_amdgcn_mfma_f32_16x16x32_bf16(af, bfv, acc[mi], 0, 0, 0);
    }
  }
  float* outp = partial + (size_t)kc*LSEQ*DST;
  #pragma unroll
  for (int mi=0;mi<2;mi++){
    int rbase = bm*128 + wave*32 + mi*16 + (lane>>4)*4;
    #pragma unroll
    for (int j=0;j<4;j++)
      outp[(size_t)(rbase+j)*DST + lm] = acc[mi][j];
  }
}

// sum the KSPLIT partials -> BsB
__global__ void reduce_bs(const float* __restrict__ partial, float* __restrict__ out, int n4){
  int i = blockIdx.x*blockDim.x + threadIdx.x;
  if (i >= n4) return;
  float4 s = ((const float4*)partial)[i];
  #pragma unroll
  for (int k=1;k<KSPLIT;k++){
    float4 v = ((const float4*)(partial + (size_t)k*LSEQ*DST))[i];
    s.x += v.x; s.y += v.y; s.z += v.z; s.w += v.w;
  }
  ((float4*)out)[i] = s;
}

// ---------------- depthwise causal conv K=4 + silu, bf16 in/out (one batch) ----------------
__global__ __launch_bounds__(256)
void conv_silu(const ushort* __restrict__ xs_raw, const float* __restrict__ w,
               const float* __restrict__ cb, ushort* __restrict__ out)
{
  int idx = blockIdx.x*256 + threadIdx.x;   // (LSEQ/8)*DI threads
  int c  = idx & (DI-1);
  int l8 = idx >> 11;                       // 0..511
  int l0 = l8*8;
  float w0=w[c*4+0], w1=w[c*4+1], w2=w[c*4+2], w3=w[c*4+3];
  float bias = cb[c];
  const ushort* base = xs_raw + c;
  float v[11];
  #pragma unroll
  for (int i=0;i<11;i++){
    int t = l0 - 3 + i;
    v[i] = (t >= 0) ? bf2f(base[(size_t)t*DI]) : 0.f;
  }
  ushort* ob = out + (size_t)l0*DI + c;
  #pragma unroll
  for (int i=0;i<8;i++){
    float acc = bias + v[i]*w0 + v[i+1]*w1 + v[i+2]*w2 + v[i+3]*w3;
    ob[(size_t)i*DI] = f2bf(fsilu(acc));
  }
}

// decay helpers: fast path builds g^(s+1) from one exp (valid when a2[s]=(s+1)*a2[0])
__device__ __forceinline__ void build_pw(float g, float* pw){
  pw[0]=g;        pw[1]=g*g;       pw[2]=pw[1]*g;    pw[3]=pw[1]*pw[1];
  pw[4]=pw[3]*g;  pw[5]=pw[3]*pw[1]; pw[6]=pw[3]*pw[2]; pw[7]=pw[3]*pw[3];
  pw[8]=pw[7]*g;  pw[9]=pw[7]*pw[1]; pw[10]=pw[7]*pw[2]; pw[11]=pw[7]*pw[3];
  pw[12]=pw[7]*pw[4]; pw[13]=pw[7]*pw[5]; pw[14]=pw[7]*pw[6]; pw[15]=pw[7]*pw[7];
}

// Carry tensors use SoA layout: hlocal/hstart[((ch*DST + s)*DI) + c]

// ---------------- scan phase 1: per-chunk local scan, h0=0 (one batch) ----------------
__global__ __launch_bounds__(256)
void scan_phase1(const ushort* __restrict__ dtb, const float* __restrict__ bsb,
                 const float* __restrict__ A2n, float* __restrict__ hlocal,
                 float* __restrict__ sumdt, const int* __restrict__ flagp)
{
  __shared__ __align__(16) float bs_s[CLEN][DST];
  const int c  = blockIdx.x*256 + threadIdx.x;
  const int ch = blockIdx.y;
  if (threadIdx.x < CLEN*DST/4)
    ((float4*)bs_s)[threadIdx.x] = ((const float4*)(bsb + (size_t)ch*CLEN*DST))[threadIdx.x];
  __syncthreads();
  float h[DST];
  #pragma unroll
  for (int s=0;s<DST;s++) h[s] = 0.f;
  float sdt = 0.f;
  const ushort* dtp = dtb + (size_t)ch*CLEN*DI + c;
  if (flagp[0] == 0){
    const float a0 = A2n[(size_t)c*DST];
    #pragma unroll 4
    for (int t=0;t<CLEN;t++){
      float d = bf2f(dtp[(size_t)t*DI]);
      sdt += d;
      float pw[DST];
      build_pw(fexp2(a0*d), pw);
      #pragma unroll
      for (int s=0;s<DST;s++) h[s] = fmaf(h[s], pw[s], bs_s[t][s]);
    }
  } else {
    float a2[DST];
    #pragma unroll
    for (int i=0;i<4;i++) *(float4*)&a2[i*4] = *(const float4*)&A2n[(size_t)c*DST + i*4];
    #pragma unroll 2
    for (int t=0;t<CLEN;t++){
      float d = bf2f(dtp[(size_t)t*DI]);
      sdt += d;
      #pragma unroll
      for (int s=0;s<DST;s++) h[s] = fmaf(h[s], fexp2(a2[s]*d), bs_s[t][s]);
    }
  }
  size_t o = (size_t)ch*DST*DI + c;
  #pragma unroll
  for (int s=0;s<DST;s++) hlocal[o + (size_t)s*DI] = h[s];
  sumdt[(size_t)ch*DI + c] = sdt;
}

// ---------------- scan phase 2: chunk-level prefix over NCHUNK chunks ----------------
__global__ void scan_phase2(const float* __restrict__ hlocal, const float* __restrict__ sumdt,
                            const float* __restrict__ A2n, float* __restrict__ hstart)
{
  int id = blockIdx.x*blockDim.x + threadIdx.x;   // DI*DST = 32768
  int c = id & (DI-1);
  int s = id >> 11;
  float a2 = A2n[(size_t)c*DST + s];
  float h = 0.f;
  for (int ch=0; ch<NCHUNK; ++ch){
    size_t o = ((size_t)ch*DST + s)*DI + c;
    hstart[o] = h;
    float sd = sumdt[(size_t)ch*DI + c];
    h = fmaf(h, fexp2(a2*sd), hlocal[o]);
  }
}

// ---------------- scan phase 3: replay with carry, emit y*silu(z) bf16 ----------------
__global__ __launch_bounds__(256)
void scan_phase3(const ushort* __restrict__ dtb, const float* __restrict__ bsb,
                 const float* __restrict__ A2n, const float* __restrict__ hstart,
                 const ushort* __restrict__ xsbf, const ushort* __restrict__ szb,
                 const float* __restrict__ Dv, ushort* __restrict__ ybf,
                 const int* __restrict__ flagp)
{
  __shared__ __align__(16) float bs_s[CLEN][DST];
  const int c  = blockIdx.x*256 + threadIdx.x;
  const int ch = blockIdx.y;
  if (threadIdx.x < CLEN*DST/4)
    ((float4*)bs_s)[threadIdx.x] = ((const float4*)(bsb + (size_t)ch*CLEN*DST))[threadIdx.x];
  __syncthreads();
  float h[DST];
  size_t ho = (size_t)ch*DST*DI + c;
  #pragma unroll
  for (int s=0;s<DST;s++) h[s] = hstart[ho + (size_t)s*DI];
  const float Dc = Dv[c];
  const size_t base = (size_t)ch*CLEN*DI + c;
  const ushort* dtp = dtb + base;
  const ushort* xp  = xsbf + base;
  const ushort* szp = szb + base;
  ushort* yp = ybf + base;
  if (flagp[0] == 0){
    const float a0 = A2n[(size_t)c*DST];
    #pragma unroll 4
    for (int t=0;t<CLEN;t++){
      float d = bf2f(dtp[(size_t)t*DI]);
      float pw[DST];
      build_pw(fexp2(a0*d), pw);
      #pragma unroll
      for (int s=0;s<DST;s++) h[s] = fmaf(h[s], pw[s], bs_s[t][s]);
      float ysum = ((h[0]+h[1])+(h[2]+h[3])) + ((h[4]+h[5])+(h[6]+h[7]))
                 + ((h[8]+h[9])+(h[10]+h[11])) + ((h[12]+h[13])+(h[14]+h[15]));
      float xv = bf2f(xp[(size_t)t*DI]);
      float yv = fmaf(Dc, xv, ysum);
      yp[(size_t)t*DI] = f2bf(yv * bf2f(szp[(size_t)t*DI]));
    }
  } else {
    float a2[DST];
    #pragma unroll
    for (int i=0;i<4;i++) *(float4*)&a2[i*4] = *(const float4*)&A2n[(size_t)c*DST + i*4];
    #pragma unroll 2
    for (int t=0;t<CLEN;t++){
      float d = bf2f(dtp[(size_t)t*DI]);
      #pragma unroll
      for (int s=0;s<DST;s++) h[s] = fmaf(h[s], fexp2(a2[s]*d), bs_s[t][s]);
      float ysum = ((h[0]+h[1])+(h[2]+h[3])) + ((h[4]+h[5])+(h[6]+h[7]))
                 + ((h[8]+h[9])+(h[10]+h[11])) + ((h[12]+h[13])+(h[14]+h[15]));
      float xv = bf2f(xp[(size_t)t*DI]);
      float yv = fmaf(Dc, xv, ysum);
      yp[(size_t)t*DI] = f2bf(yv * bf2f(szp[(size_t)t*DI]));
    }
  }
}

// ---------------- launch ----------------
extern "C" void kernel_launch(void* const* d_in, const int* in_sizes, int n_in,
                              void* d_out, int out_size, void* d_ws, size_t ws_size,
                              hipStream_t stream)
{
  if (n_in < 10) return;
  const float* x     = (const float*)d_in[0];
  const float* W_in  = (const float*)d_in[1];
  const float* convw = (const float*)d_in[2];
  const float* convb = (const float*)d_in[3];
  const float* A_log = (const float*)d_in[4];
  const float* Dvec  = (const float*)d_in[5];
  const float* W_x   = (const float*)d_in[6];
  const float* W_dt  = (const float*)d_in[7];
  const float* b_dt  = (const float*)d_in[8];
  const float* W_out = (const float*)d_in[9];
  float* out = (float*)d_out;

  char* p = (char*)d_ws;
  auto alloc = [&](size_t n){ char* r = p; p += (n + 255) & ~(size_t)255; return r; };
  // weights (once)
  ushort* WinT   = (ushort*)alloc((size_t)(2*DI)*DMODEL*2);   //  8.4 MB
  ushort* WdtT   = (ushort*)alloc((size_t)DI*DI*2);           //  8.4 MB
  ushort* WoutT  = (ushort*)alloc((size_t)DMODEL*DI*2);       //  4.2 MB
  ushort* WxT    = (ushort*)alloc((size_t)DST*DI*2);          //  64 KB
  float*  A2n    = (float*)alloc((size_t)DI*DST*4);           //  0.1 MB
  int*    flag   = (int*)alloc(256);
  // per-batch activations (reused across the 4 batches)
  ushort* xbf    = (ushort*)alloc((size_t)LSEQ*DMODEL*2);     //  8.4 MB
  ushort* xsr    = (ushort*)alloc((size_t)LSEQ*DI*2);         // 16.8 MB raw xs; dead after conv -> reused as hlocal
  ushort* szb    = (ushort*)alloc((size_t)LSEQ*DI*2);         // 16.8 MB silu(z)
  ushort* xsb    = (ushort*)alloc((size_t)LSEQ*DI*2);         // 16.8 MB conv+silu
  ushort* dtb    = (ushort*)alloc((size_t)LSEQ*DI*2);         // 16.8 MB dt
  ushort* ybf    = (ushort*)alloc((size_t)LSEQ*DI*2);         // 16.8 MB y
  float*  BsB    = (float*)alloc((size_t)LSEQ*DST*4);         //  0.3 MB
  float*  hstart = (float*)alloc((size_t)NCHUNK*DI*DST*4);    // 16.8 MB (aliased by BsP pre-scan)
  float*  sumdt  = (float*)alloc((size_t)NCHUNK*DI*4);        //  1.0 MB
  if ((size_t)(p - (char*)d_ws) > ws_size) return;   // ws too small: no OOB
  float* hlocal = (float*)xsr;   // 16.8 MB == xsr size; xsr dead after conv,
                                 // hlocal dead after phase2 (before next batch's gemm0 rewrites xsr)
  float* BsP = hstart;           // 4.2 MB < 16.8 MB; consumed by reduce_bs before phase2 writes hstart

  // weight prep
  transpose_cast<<<dim3((2*DI)/32, DMODEL/32), dim3(32,8), 0, stream>>>(W_in, WinT, DMODEL, 2*DI);
  transpose_cast<<<dim3(DI/32, DI/32), dim3(32,8), 0, stream>>>(W_dt, WdtT, DI, DI);
  transpose_cast<<<dim3(DMODEL/32, DI/32), dim3(32,8), 0, stream>>>(W_out, WoutT, DI, DMODEL);
  transpose_cast<<<dim3(1, DI/32), dim3(32,8), 0, stream>>>(W_x, WxT, DI, DST);
  prep_a2<<<(DI*DST + 255)/256, 256, 0, stream>>>(A_log, A2n, DI*DST);
  hipMemsetAsync(flag, 0, 4, stream);
  check_a2<<<DI/256, 256, 0, stream>>>(A2n, flag);

  for (int b = 0; b < NBATCH; ++b) {
    const float* xb = x + (size_t)b*LSEQ*DMODEL;
    float* outb = out + (size_t)b*LSEQ*DMODEL;
    // cast x -> bf16
    cast_f32_bf16<<<(LSEQ*DMODEL/4 + 255)/256, 256, 0, stream>>>(xb, xbf, LSEQ*DMODEL/4);
    // xz = x @ W_in ; xs raw bf16 + silu(z) bf16  (256^2 tile)
    gemm8<256,256,2,4,0><<<dim3(4096/256, 4096/256), 512, 0, stream>>>(xbf, WinT, DMODEL, xsr, szb, nullptr);
    // depthwise conv + silu -> bf16
    conv_silu<<<(LSEQ/8)*DI/256, 256, 0, stream>>>(xsr, convw, convb, xsb);
    // dt = softplus(xs @ W_dt + b_dt) -> bf16  (128x256)
    gemm8<128,256,2,4,1><<<dim3(2048/256, 4096/128), 512, 0, stream>>>(xsb, WdtT, DI, dtb, nullptr, b_dt);
    // Bs = xs @ W_x via split-K partials + reduce -> f32
    gemm_bs<<<dim3(KSPLIT, LSEQ/128), 256, 0, stream>>>(xsb, WxT, BsP);
    reduce_bs<<<(LSEQ*DST/4 + 255)/256, 256, 0, stream>>>(BsP, BsB, LSEQ*DST/4);
    // chunked scan (hlocal lives in xsr's storage; SoA carry layout)
    scan_phase1<<<dim3(DI/256, NCHUNK), 256, 0, stream>>>(dtb, BsB, A2n, hlocal, sumdt, flag);
    scan_phase2<<<(DI*DST)/256, 256, 0, stream>>>(hlocal, sumdt, A2n, hstart);
    scan_phase3<<<dim3(DI/256, NCHUNK), 256, 0, stream>>>(dtb, BsB, A2n, hstart, xsb, szb, Dvec, ybf, flag);
    // out = y @ W_out (f32)  (128x128)
    gemm8<128,128,2,4,2><<<dim3(1024/128, 4096/128), 512, 0, stream>>>(ybf, WoutT, DI, outb, nullptr, nullptr);
  }
}